// Round 1
// baseline (432.391 us; speedup 1.0000x reference)
//
#include <hip/hip_runtime.h>
#include <cstdint>
#include <cstddef>

#define NN 8192
#define FIN 128
#define FOUT 64

typedef __attribute__((ext_vector_type(8))) short short8;
typedef __attribute__((ext_vector_type(4))) float f32x4;

__device__ __forceinline__ unsigned short f32_to_bf16_bits(float f) {
    union { float f; uint32_t u; } c; c.f = f;
    uint32_t u = c.u;
    u += 0x7fffu + ((u >> 16) & 1u);   // RNE
    return (unsigned short)(u >> 16);
}

__device__ __forceinline__ unsigned int pack_bf16(float lo, float hi) {
    return (unsigned int)f32_to_bf16_bits(lo) |
           ((unsigned int)f32_to_bf16_bits(hi) << 16);
}

// Kernel 1: Wh = x @ W^T (bf16, stored transposed [f][i]); Wh1 = Wh@a1; Wh2 = Wh@a2
__global__ __launch_bounds__(256) void gat_prep(
    const float* __restrict__ x, const float* __restrict__ W,
    const float* __restrict__ a, unsigned short* __restrict__ WhT,
    float* __restrict__ Wh1, float* __restrict__ Wh2)
{
    const int t    = threadIdx.x;
    const int f    = t & 63;        // lane = feature
    const int iloc = t >> 6;        // wave = local row
    const int i    = blockIdx.x * 4 + iloc;

    const float4* x4 = (const float4*)(x + (size_t)i * FIN);  // wave-uniform
    const float4* w4 = (const float4*)(W + (size_t)f * FIN);

    float acc = 0.f;
#pragma unroll
    for (int k = 0; k < FIN / 4; ++k) {
        float4 xv = x4[k];
        float4 wv = w4[k];
        acc += xv.x * wv.x + xv.y * wv.y + xv.z * wv.z + xv.w * wv.w;
    }

    WhT[(size_t)f * NN + i] = f32_to_bf16_bits(acc);

    float r1 = acc * a[f];
    float r2 = acc * a[64 + f];
#pragma unroll
    for (int m = 1; m < 64; m <<= 1) {
        r1 += __shfl_xor(r1, m, 64);
        r2 += __shfl_xor(r2, m, 64);
    }
    if (f == 0) { Wh1[i] = r1; Wh2[i] = r2; }
}

// Kernel 2: per block: 16 rows. Each wave owns a j-quarter (K split), lanes
// compute P entries directly in MFMA A-fragment layout; B from global (L2-hot
// WhT). No LDS / no syncthreads in the K loop. Epilogue reduces 4 waves.
__global__ __launch_bounds__(256) void gat_attn(
    const int* __restrict__ adj, const unsigned short* __restrict__ WhT,
    const float* __restrict__ Wh1, const float* __restrict__ Wh2,
    float* __restrict__ out)
{
    __shared__ float lds_C[4][16][64];
    __shared__ float lds_tot[4][16];

    const int tid  = threadIdx.x;
    const int wave = tid >> 6;
    const int lane = tid & 63;
    const int il   = lane & 15;     // A-fragment row (i)
    const int q    = lane >> 4;     // quad -> k offset q*8
    const int i0   = blockIdx.x * 16;
    const int i    = i0 + il;

    const float wh1    = Wh1[i];
    const int   jbase  = wave * 32 + q * 8;
    const int* __restrict__ adjrow = adj + (size_t)i * NN;

    // B row pointers for the 4 N-tiles (f = nt*16 + il), contiguous in j
    const short8* bp0 = (const short8*)(WhT + (size_t)(0  + il) * NN);
    const short8* bp1 = (const short8*)(WhT + (size_t)(16 + il) * NN);
    const short8* bp2 = (const short8*)(WhT + (size_t)(32 + il) * NN);
    const short8* bp3 = (const short8*)(WhT + (size_t)(48 + il) * NN);

    f32x4 acc0 = {0.f, 0.f, 0.f, 0.f};
    f32x4 acc1 = {0.f, 0.f, 0.f, 0.f};
    f32x4 acc2 = {0.f, 0.f, 0.f, 0.f};
    f32x4 acc3 = {0.f, 0.f, 0.f, 0.f};
    float tot = 0.f;

    for (int tt = 0; tt < 64; ++tt) {
        const int j = tt * 128 + jbase;

        const int4   av0 = *(const int4*)(adjrow + j);
        const int4   av1 = *(const int4*)(adjrow + j + 4);
        const float4 w20 = *(const float4*)(Wh2 + j);
        const float4 w21 = *(const float4*)(Wh2 + j + 4);

        float wv[8];
#define CALC(idx, adjv, wh2v)                                          \
        {                                                              \
            float s = wh1 + (wh2v);                                    \
            float e = fmaxf(s, 0.2f * s);      /* leaky_relu 0.2 */    \
            float v = ((adjv) > 0) ? __expf(e) : 0.f;                  \
            tot += v;                                                  \
            wv[idx] = v;                                               \
        }
        CALC(0, av0.x, w20.x) CALC(1, av0.y, w20.y)
        CALC(2, av0.z, w20.z) CALC(3, av0.w, w20.w)
        CALC(4, av1.x, w21.x) CALC(5, av1.y, w21.y)
        CALC(6, av1.z, w21.z) CALC(7, av1.w, w21.w)
#undef CALC

        union { short8 v; unsigned int u[4]; } af;
        af.u[0] = pack_bf16(wv[0], wv[1]);
        af.u[1] = pack_bf16(wv[2], wv[3]);
        af.u[2] = pack_bf16(wv[4], wv[5]);
        af.u[3] = pack_bf16(wv[6], wv[7]);

        const int jb = j >> 3;
        const short8 b0 = bp0[jb];
        const short8 b1 = bp1[jb];
        const short8 b2 = bp2[jb];
        const short8 b3 = bp3[jb];

        acc0 = __builtin_amdgcn_mfma_f32_16x16x32_bf16(af.v, b0, acc0, 0, 0, 0);
        acc1 = __builtin_amdgcn_mfma_f32_16x16x32_bf16(af.v, b1, acc1, 0, 0, 0);
        acc2 = __builtin_amdgcn_mfma_f32_16x16x32_bf16(af.v, b2, acc2, 0, 0, 0);
        acc3 = __builtin_amdgcn_mfma_f32_16x16x32_bf16(af.v, b3, acc3, 0, 0, 0);
    }

    // row-total reduction: lanes {il, il+16, il+32, il+48} hold partials
    tot += __shfl_xor(tot, 16, 64);
    tot += __shfl_xor(tot, 32, 64);
    if (lane < 16) lds_tot[wave][lane] = tot;

    // C/D layout: col = lane&15 (f within tile), row = q*4 + reg (i)
#pragma unroll
    for (int r = 0; r < 4; ++r) {
        lds_C[wave][q * 4 + r][0 * 16 + il] = acc0[r];
        lds_C[wave][q * 4 + r][1 * 16 + il] = acc1[r];
        lds_C[wave][q * 4 + r][2 * 16 + il] = acc2[r];
        lds_C[wave][q * 4 + r][3 * 16 + il] = acc3[r];
    }
    __syncthreads();

#pragma unroll
    for (int e = 0; e < 4; ++e) {
        const int idx = e * 256 + tid;
        const int ii = idx >> 6;
        const int ff = idx & 63;
        float s = lds_C[0][ii][ff] + lds_C[1][ii][ff] +
                  lds_C[2][ii][ff] + lds_C[3][ii][ff];
        float ts = lds_tot[0][ii] + lds_tot[1][ii] +
                   lds_tot[2][ii] + lds_tot[3][ii];
        float p = s / ts;
        out[(size_t)(i0 + ii) * FOUT + ff] = (p > 0.f) ? p : (__expf(p) - 1.f);
    }
}

extern "C" void kernel_launch(void* const* d_in, const int* in_sizes, int n_in,
                              void* d_out, int out_size, void* d_ws, size_t ws_size,
                              hipStream_t stream) {
    const float* x   = (const float*)d_in[0];
    const int*   adj = (const int*)d_in[1];
    const float* W   = (const float*)d_in[2];
    const float* a   = (const float*)d_in[3];
    float* out = (float*)d_out;

    unsigned short* WhT = (unsigned short*)d_ws;                       // 1 MB
    float* Wh1 = (float*)((char*)d_ws + (size_t)1048576);              // 32 KB
    float* Wh2 = (float*)((char*)d_ws + (size_t)1048576 + 32768);      // 32 KB

    gat_prep<<<dim3(NN / 4), dim3(256), 0, stream>>>(x, W, a, WhT, Wh1, Wh2);
    gat_attn<<<dim3(NN / 16), dim3(256), 0, stream>>>(adj, WhT, Wh1, Wh2, out);
}

// Round 2
// 423.425 us; speedup vs baseline: 1.0212x; 1.0212x over previous
//
#include <hip/hip_runtime.h>
#include <cstdint>
#include <cstddef>

#define NN 8192
#define FIN 128
#define FOUT 64

typedef __attribute__((ext_vector_type(8))) short short8;
typedef __attribute__((ext_vector_type(4))) float f32x4;

__device__ __forceinline__ unsigned short f32_to_bf16_bits(float f) {
    union { float f; uint32_t u; } c; c.f = f;
    uint32_t u = c.u;
    u += 0x7fffu + ((u >> 16) & 1u);   // RNE
    return (unsigned short)(u >> 16);
}

__device__ __forceinline__ unsigned int pack_bf16(float lo, float hi) {
    return (unsigned int)f32_to_bf16_bits(lo) |
           ((unsigned int)f32_to_bf16_bits(hi) << 16);
}

// Kernel 1: Wh = x @ W^T (bf16, stored transposed [f][i]); Wh1 = Wh@a1; Wh2 = Wh@a2
__global__ __launch_bounds__(256) void gat_prep(
    const float* __restrict__ x, const float* __restrict__ W,
    const float* __restrict__ a, unsigned short* __restrict__ WhT,
    float* __restrict__ Wh1, float* __restrict__ Wh2)
{
    const int t    = threadIdx.x;
    const int f    = t & 63;        // lane = feature
    const int iloc = t >> 6;        // wave = local row
    const int i    = blockIdx.x * 4 + iloc;

    const float4* x4 = (const float4*)(x + (size_t)i * FIN);  // wave-uniform
    const float4* w4 = (const float4*)(W + (size_t)f * FIN);

    float acc = 0.f;
#pragma unroll
    for (int k = 0; k < FIN / 4; ++k) {
        float4 xv = x4[k];
        float4 wv = w4[k];
        acc += xv.x * wv.x + xv.y * wv.y + xv.z * wv.z + xv.w * wv.w;
    }

    WhT[(size_t)f * NN + i] = f32_to_bf16_bits(acc);

    float r1 = acc * a[f];
    float r2 = acc * a[64 + f];
#pragma unroll
    for (int m = 1; m < 64; m <<= 1) {
        r1 += __shfl_xor(r1, m, 64);
        r2 += __shfl_xor(r2, m, 64);
    }
    if (f == 0) { Wh1[i] = r1; Wh2[i] = r2; }
}

// Kernel 2: 1024 blocks = (512 row-tiles) x (2 j-halves) -> 4 blocks/CU,
// 16 waves/CU. Each wave owns a 32-wide j-strip within its half; lanes build
// P directly in MFMA A-fragment layout. Explicit 2-stage software pipeline:
// prefetch next iteration's adj/Wh2/B while computing the current one.
// Writes PARTIAL C (16x64) + partial row-sums; combine kernel finishes.
__global__ __launch_bounds__(256, 4) void gat_attn(
    const int* __restrict__ adj, const unsigned short* __restrict__ WhT,
    const float* __restrict__ Wh1, const float* __restrict__ Wh2,
    float* __restrict__ Cpart, float* __restrict__ Tpart)
{
    __shared__ float lds_C[4][16][68];   // +4 pad: breaks 4-way write conflict
    __shared__ float lds_tot[4][16];

    const int tid  = threadIdx.x;
    const int wave = tid >> 6;
    const int lane = tid & 63;
    const int il   = lane & 15;     // A-fragment row (i)
    const int q    = lane >> 4;     // quad -> k offset q*8
    const int rt   = blockIdx.x >> 1;
    const int jh   = blockIdx.x & 1;     // j-half
    const int i0   = rt * 16;
    const int i    = i0 + il;

    const float wh1   = Wh1[i];
    const int   jbase = jh * 4096 + wave * 32 + q * 8;
    const int* __restrict__ adjrow = adj + (size_t)i * NN;

    const short8* bp0 = (const short8*)(WhT + (size_t)(0  + il) * NN);
    const short8* bp1 = (const short8*)(WhT + (size_t)(16 + il) * NN);
    const short8* bp2 = (const short8*)(WhT + (size_t)(32 + il) * NN);
    const short8* bp3 = (const short8*)(WhT + (size_t)(48 + il) * NN);

    f32x4 acc0 = {0.f, 0.f, 0.f, 0.f};
    f32x4 acc1 = {0.f, 0.f, 0.f, 0.f};
    f32x4 acc2 = {0.f, 0.f, 0.f, 0.f};
    f32x4 acc3 = {0.f, 0.f, 0.f, 0.f};
    float tot = 0.f;

    // ---- pipeline prologue: load iter 0 ----
    int4   av0 = *(const int4*)(adjrow + jbase);
    int4   av1 = *(const int4*)(adjrow + jbase + 4);
    float4 w20 = *(const float4*)(Wh2 + jbase);
    float4 w21 = *(const float4*)(Wh2 + jbase + 4);
    int jb = jbase >> 3;
    short8 b0 = bp0[jb];
    short8 b1 = bp1[jb];
    short8 b2 = bp2[jb];
    short8 b3 = bp3[jb];

    for (int tt = 0; tt < 32; ++tt) {
        // ---- prefetch iter tt+1 (wraps to 0 on last iter; result unused) ----
        const int jn = jbase + (((tt + 1) & 31) << 7);   // stride 128/iter
        const int4   nav0 = *(const int4*)(adjrow + jn);
        const int4   nav1 = *(const int4*)(adjrow + jn + 4);
        const float4 nw20 = *(const float4*)(Wh2 + jn);
        const float4 nw21 = *(const float4*)(Wh2 + jn + 4);
        const int jnb = jn >> 3;
        const short8 nb0 = bp0[jnb];
        const short8 nb1 = bp1[jnb];
        const short8 nb2 = bp2[jnb];
        const short8 nb3 = bp3[jnb];

        // ---- compute iter tt ----
        float wv[8];
#define CALC(idx, adjv, wh2v)                                          \
        {                                                              \
            float s = wh1 + (wh2v);                                    \
            float e = fmaxf(s, 0.2f * s);      /* leaky_relu 0.2 */    \
            float v = ((adjv) > 0) ? __expf(e) : 0.f;                  \
            tot += v;                                                  \
            wv[idx] = v;                                               \
        }
        CALC(0, av0.x, w20.x) CALC(1, av0.y, w20.y)
        CALC(2, av0.z, w20.z) CALC(3, av0.w, w20.w)
        CALC(4, av1.x, w21.x) CALC(5, av1.y, w21.y)
        CALC(6, av1.z, w21.z) CALC(7, av1.w, w21.w)
#undef CALC

        union { short8 v; unsigned int u[4]; } af;
        af.u[0] = pack_bf16(wv[0], wv[1]);
        af.u[1] = pack_bf16(wv[2], wv[3]);
        af.u[2] = pack_bf16(wv[4], wv[5]);
        af.u[3] = pack_bf16(wv[6], wv[7]);

        acc0 = __builtin_amdgcn_mfma_f32_16x16x32_bf16(af.v, b0, acc0, 0, 0, 0);
        acc1 = __builtin_amdgcn_mfma_f32_16x16x32_bf16(af.v, b1, acc1, 0, 0, 0);
        acc2 = __builtin_amdgcn_mfma_f32_16x16x32_bf16(af.v, b2, acc2, 0, 0, 0);
        acc3 = __builtin_amdgcn_mfma_f32_16x16x32_bf16(af.v, b3, acc3, 0, 0, 0);

        // ---- rotate pipeline registers ----
        av0 = nav0; av1 = nav1; w20 = nw20; w21 = nw21;
        b0 = nb0; b1 = nb1; b2 = nb2; b3 = nb3;
    }

    // row-total reduction: lanes {il, il+16, il+32, il+48} hold partials
    tot += __shfl_xor(tot, 16, 64);
    tot += __shfl_xor(tot, 32, 64);
    if (lane < 16) lds_tot[wave][lane] = tot;

    // C/D layout: col = lane&15 (f within tile), row = q*4 + reg (i)
#pragma unroll
    for (int r = 0; r < 4; ++r) {
        lds_C[wave][q * 4 + r][0 * 16 + il] = acc0[r];
        lds_C[wave][q * 4 + r][1 * 16 + il] = acc1[r];
        lds_C[wave][q * 4 + r][2 * 16 + il] = acc2[r];
        lds_C[wave][q * 4 + r][3 * 16 + il] = acc3[r];
    }
    __syncthreads();

#pragma unroll
    for (int e = 0; e < 4; ++e) {
        const int idx = e * 256 + tid;
        const int ii = idx >> 6;
        const int ff = idx & 63;
        float s = lds_C[0][ii][ff] + lds_C[1][ii][ff] +
                  lds_C[2][ii][ff] + lds_C[3][ii][ff];
        Cpart[((size_t)jh * NN + i0 + ii) * FOUT + ff] = s;
        if (ff == 0) {
            float ts = lds_tot[0][ii] + lds_tot[1][ii] +
                       lds_tot[2][ii] + lds_tot[3][ii];
            Tpart[(size_t)jh * NN + i0 + ii] = ts;
        }
    }
}

// Kernel 3: combine the two j-half partials, normalize, ELU.
__global__ __launch_bounds__(256) void gat_combine(
    const float* __restrict__ Cpart, const float* __restrict__ Tpart,
    float* __restrict__ out)
{
    const int idx = blockIdx.x * 256 + threadIdx.x;   // over NN*FOUT
    const int i = idx >> 6;                            // row
    const float c = Cpart[idx] + Cpart[(size_t)NN * FOUT + idx];
    const float t = Tpart[i] + Tpart[NN + i];
    const float p = c / t;
    out[idx] = (p > 0.f) ? p : (__expf(p) - 1.f);
}

extern "C" void kernel_launch(void* const* d_in, const int* in_sizes, int n_in,
                              void* d_out, int out_size, void* d_ws, size_t ws_size,
                              hipStream_t stream) {
    const float* x   = (const float*)d_in[0];
    const int*   adj = (const int*)d_in[1];
    const float* W   = (const float*)d_in[2];
    const float* a   = (const float*)d_in[3];
    float* out = (float*)d_out;

    char* ws = (char*)d_ws;
    unsigned short* WhT = (unsigned short*)ws;                 // 1 MB @ 0
    float* Wh1   = (float*)(ws + (size_t)1048576);             // 32 KB
    float* Wh2   = (float*)(ws + (size_t)1048576 + 32768);     // 32 KB
    float* Cpart = (float*)(ws + (size_t)2097152);             // 4 MB (2 halves)
    float* Tpart = (float*)(ws + (size_t)6291456);             // 64 KB

    gat_prep<<<dim3(NN / 4), dim3(256), 0, stream>>>(x, W, a, WhT, Wh1, Wh2);
    gat_attn<<<dim3(NN / 16 * 2), dim3(256), 0, stream>>>(adj, WhT, Wh1, Wh2, Cpart, Tpart);
    gat_combine<<<dim3(NN * FOUT / 256), dim3(256), 0, stream>>>(Cpart, Tpart, out);
}